// Round 5
// baseline (4660.262 us; speedup 1.0000x reference)
//
#include <hip/hip_runtime.h>

typedef unsigned short u16;
typedef unsigned long long u64;
typedef short bf16x8 __attribute__((ext_vector_type(8)));
typedef float f32x4 __attribute__((ext_vector_type(4)));

#define B_ 256
#define T_ 512
#define I_ 64
#define H_ 512
#define RING 32

// ---------------- ws layout (bytes) ----------------
// Private poll lines (1 spinning wave per 256B line, 1 writer per slot):
//   REC0[wid][64]: L0 worker wid polls. slots 0-31 = L0 rec flags (producer jn'),
//                  slots 32-63 = ring credits from L1 worker jn' (slot 32+jn').
//   IN1 [wid][64]: L1 wave0 polls. slots 0-31 = h1-ready from L0 worker jn'.
//   REC1[wid][64]: L1 wave1 polls. slots 0-31 = L1 rec flags from L1 wave0 jn'.
// h1 ring: [RING][k8=64][row 256][8] bf16 — L0 writes slot t, L0 rec reads t-1,
// L1 input reads t. hx (L1 h2): [2 parity][k8][row][8] bf16.
#define OFF_REC0  0u
#define OFF_IN1   65536u
#define OFF_REC1  131072u
#define OFF_B0    196608u      // 2048 f32
#define OFF_B1    204800u      // 2048 f32
#define OFF_WIH0  212992u      // 2048x64 bf16
#define OFF_WHH0  475136u      // 2048x512 bf16
#define OFF_WIH1  2572288u     // 2048x512 bf16
#define OFF_WHH1  4669440u     // 2048x512 bf16
#define OFF_HX1   6766592u     // 2 x [64][256][8] bf16
#define OFF_H1R   7290880u     // RING x [64][256][8] bf16
#define WS_NEEDED 15679488u

#define AQ __ATOMIC_RELAXED
#define SC __HIP_MEMORY_SCOPE_AGENT

static __device__ __forceinline__ u16 f2b(float f) {
  union { float f; unsigned u; } v; v.f = f;
  unsigned r = (v.u + 0x7FFFu + ((v.u >> 16) & 1u)) >> 16;
  return (u16)r;
}
static __device__ __forceinline__ float sigm(float x) { return 1.f / (1.f + __expf(-x)); }
static __device__ __forceinline__ float tanh_(float x) { return 1.f - 2.f / (__expf(2.f * x) + 1.f); }

// ---------------- prep ----------------
__global__ void prep_kernel(const float* __restrict__ Wih0, const float* __restrict__ Whh0,
                            const float* __restrict__ bih0, const float* __restrict__ bhh0,
                            const float* __restrict__ Wih1, const float* __restrict__ Whh1,
                            const float* __restrict__ bih1, const float* __restrict__ bhh1,
                            const float* __restrict__ bfc, float* __restrict__ out,
                            char* __restrict__ ws) {
  unsigned* flags = (unsigned*)(ws + OFF_REC0);  // REC0+IN1+REC1: 49152 u32
  float* b0 = (float*)(ws + OFF_B0);
  float* b1 = (float*)(ws + OFF_B1);
  u16* wih0b = (u16*)(ws + OFF_WIH0);
  u16* whh0b = (u16*)(ws + OFF_WHH0);
  u16* wih1b = (u16*)(ws + OFF_WIH1);
  u16* whh1b = (u16*)(ws + OFF_WHH1);

  long long i = (long long)blockIdx.x * 256 + threadIdx.x;
  if (i < 49152) { __hip_atomic_store(&flags[i], 0u, AQ, SC); return; }
  i -= 49152;
  if (i < 256) { out[i] = bfc[0]; return; }
  i -= 256;
  if (i < 2048) { b0[i] = bih0[i] + bhh0[i]; return; }
  i -= 2048;
  if (i < 2048) { b1[i] = bih1[i] + bhh1[i]; return; }
  i -= 2048;
  if (i < 131072) { wih0b[i] = f2b(Wih0[i]); return; }
  i -= 131072;
  if (i < 1048576) { whh0b[i] = f2b(Whh0[i]); return; }
  i -= 1048576;
  if (i < 1048576) { wih1b[i] = f2b(Wih1[i]); return; }
  i -= 1048576;
  if (i < 1048576) { whh1b[i] = f2b(Whh1[i]); return; }
}

// weight slice preload: [16 ksteps][4 gates] B-fragments -> 256 VGPR
static __device__ __forceinline__ void loadW(bf16x8 (&W)[16][4], const u16* __restrict__ Wb,
                                             int jn, int quad, int l15) {
#pragma unroll
  for (int ks = 0; ks < 16; ++ks)
#pragma unroll
    for (int nt = 0; nt < 4; ++nt)
      W[ks][nt] = *(const bf16x8*)&Wb[(size_t)(nt * 512 + jn * 16 + l15) * 512 +
                                      ks * 32 + quad * 8];
}

// K=512 GEMM from a transposed [k8][row][8] bf16 buffer, weights in VGPRs
static __device__ __forceinline__ void gemm512(const u64* __restrict__ hq,
                                               const bf16x8 (&W)[16][4], f32x4 (&acc)[2][4],
                                               int ib, int quad, int l15) {
#pragma unroll
  for (int half = 0; half < 2; ++half) {
    bf16x8 af[8][2];
#pragma unroll
    for (int r = 0; r < 8; ++r) {
      const int ks = half * 8 + r;
#pragma unroll
      for (int mt = 0; mt < 2; ++mt) {
        const u64* p = hq + (size_t)((ks * 4 + quad) * 256 + ib * 32 + mt * 16 + l15) * 2;
        union { u64 q[2]; bf16x8 v; } u;
        u.q[0] = __hip_atomic_load(p, AQ, SC);
        u.q[1] = __hip_atomic_load(p + 1, AQ, SC);
        af[r][mt] = u.v;
      }
    }
#pragma unroll
    for (int r = 0; r < 8; ++r)
#pragma unroll
      for (int mt = 0; mt < 2; ++mt)
#pragma unroll
        for (int nt = 0; nt < 4; ++nt)
          acc[mt][nt] = __builtin_amdgcn_mfma_f32_16x16x32_bf16(af[r][mt], W[half * 8 + r][nt],
                                                                acc[mt][nt], 0, 0, 0);
  }
}

// gates -> c/h update in MFMA D-layout (lane: col=l15, rows quad*4+rr+16mt);
// pack col pairs via shfl_xor(1); even-l15 lanes store u32 into [k8][row][8] buffer.
static __device__ __forceinline__ void elem_store(f32x4 (&acc)[2][4], const float (&bias4)[4],
                                                  float (&cst)[2][4], float (&hvv)[2][4],
                                                  unsigned* __restrict__ dst32, unsigned base,
                                                  int k8, int rowbase, int l15) {
#pragma unroll
  for (int mt = 0; mt < 2; ++mt)
#pragma unroll
    for (int rr = 0; rr < 4; ++rr) {
      float iv = sigm(acc[mt][0][rr] + bias4[0]);
      float fv = sigm(acc[mt][1][rr] + bias4[1]);
      float gv = tanh_(acc[mt][2][rr] + bias4[2]);
      float ov = sigm(acc[mt][3][rr] + bias4[3]);
      float cn = fv * cst[mt][rr] + iv * gv;
      cst[mt][rr] = cn;
      float hv = ov * tanh_(cn);
      hvv[mt][rr] = hv;
      float hp = __shfl_xor(hv, 1);
      if (!(l15 & 1)) {
        unsigned pk = (unsigned)f2b(hv) | ((unsigned)f2b(hp) << 16);
        __hip_atomic_store(&dst32[base + (unsigned)(k8 * 256 + rowbase + mt * 16 + rr) * 4 +
                                  ((l15 & 7) >> 1)], pk, AQ, SC);
      }
    }
}

// ---------------- fused 2-layer LSTM: autonomous wave workers, no loop barriers ----------
// Grid 192 x 256thr: bx<64 = L0 (4 single-wave workers/block), bx>=64 = L1 (2 two-wave
// worker pairs/block). Worker (ib=wid>>5, jn=wid&31): 32 rows x 16 h-cols, K=512 in VGPR.
__global__ __launch_bounds__(256, 1) void lstm_fused(
    const float* __restrict__ x,
    const u16* __restrict__ wih0, const u16* __restrict__ whh0, const float* __restrict__ b0,
    const u16* __restrict__ wih1, const u16* __restrict__ whh1, const float* __restrict__ b1,
    unsigned* __restrict__ hx32, u16* __restrict__ h1ring,
    const float* __restrict__ Wfc, float* __restrict__ out,
    unsigned* __restrict__ REC0, unsigned* __restrict__ IN1, unsigned* __restrict__ REC1)
{
  __shared__ __align__(16) float Pp[2][2][32 * 68];  // [pair][dbuf][32 rows x 68-pad]
  __shared__ unsigned seqf[2];
  const int wv = threadIdx.x >> 6;
  const int lane = threadIdx.x & 63;
  const int quad = lane >> 4;
  const int l15 = lane & 15;
  if (threadIdx.x == 0) { seqf[0] = 0u; seqf[1] = 0u; }
  __syncthreads();  // only barrier in the kernel (seqf init)
  const f32x4 zf = {0.f, 0.f, 0.f, 0.f};

  if (blockIdx.x < 64) {
    // ================= L0: single-wave worker =================
    const int wid = blockIdx.x * 4 + wv;
    const int ib = wid >> 5, jn = wid & 31;
    bf16x8 Bh[16][4];
    loadW(Bh, whh0, jn, quad, l15);
    bf16x8 Bx0[2][4];
#pragma unroll
    for (int ks = 0; ks < 2; ++ks)
#pragma unroll
      for (int nt = 0; nt < 4; ++nt)
        Bx0[ks][nt] = *(const bf16x8*)&wih0[(size_t)(nt * 512 + jn * 16 + l15) * 64 +
                                            ks * 32 + quad * 8];
    float bias4[4];
#pragma unroll
    for (int g = 0; g < 4; ++g) bias4[g] = b0[g * 512 + jn * 16 + l15];
    float cst[2][4] = {{0.f, 0.f, 0.f, 0.f}, {0.f, 0.f, 0.f, 0.f}};
    float hvv[2][4];
    const unsigned* pollP = REC0 + (unsigned)wid * 64 + lane;
    unsigned* sigP = (lane < 32)
        ? (REC0 + (unsigned)(ib * 32 + lane) * 64 + jn)
        : (IN1 + (unsigned)(ib * 32 + (lane - 32)) * 64 + jn);
    const u64* ring64 = (const u64*)h1ring;
    unsigned* ring32 = (unsigned*)h1ring;
    const int k8 = jn * 2 + (l15 >> 3);
    const int rowbase = ib * 32 + quad * 4;

    for (int t = 0; t < T_; ++t) {
      // x(t) loads issued before the poll (latency hides under the spin)
      float4 xr[2][4];
#pragma unroll
      for (int mt = 0; mt < 2; ++mt) {
        const float* xp = x + ((size_t)(ib * 32 + mt * 16 + l15) * T_ + t) * 64;
#pragma unroll
        for (int ks = 0; ks < 2; ++ks) {
          xr[mt][ks * 2 + 0] = *(const float4*)(xp + ks * 32 + quad * 8);
          xr[mt][ks * 2 + 1] = *(const float4*)(xp + ks * 32 + quad * 8 + 4);
        }
      }
      if (t) {
        const unsigned tg = (lane < 32) ? (unsigned)t
                            : ((t >= RING) ? (unsigned)(t - RING + 1) : 0u);
        while (__any(__hip_atomic_load(pollP, AQ, SC) < tg)) {}
      }
      f32x4 acc[2][4];
#pragma unroll
      for (int mt = 0; mt < 2; ++mt)
#pragma unroll
        for (int nt = 0; nt < 4; ++nt) acc[mt][nt] = zf;
      // input GEMM (K=64) from registers
#pragma unroll
      for (int mt = 0; mt < 2; ++mt)
#pragma unroll
        for (int ks = 0; ks < 2; ++ks) {
          union { unsigned u[4]; bf16x8 v; } P;
          float4 a = xr[mt][ks * 2], b2 = xr[mt][ks * 2 + 1];
          P.u[0] = (unsigned)f2b(a.x) | ((unsigned)f2b(a.y) << 16);
          P.u[1] = (unsigned)f2b(a.z) | ((unsigned)f2b(a.w) << 16);
          P.u[2] = (unsigned)f2b(b2.x) | ((unsigned)f2b(b2.y) << 16);
          P.u[3] = (unsigned)f2b(b2.z) | ((unsigned)f2b(b2.w) << 16);
#pragma unroll
          for (int nt = 0; nt < 4; ++nt)
            acc[mt][nt] = __builtin_amdgcn_mfma_f32_16x16x32_bf16(P.v, Bx0[ks][nt],
                                                                  acc[mt][nt], 0, 0, 0);
        }
      // recurrent GEMM from ring slot t-1
      if (t)
        gemm512(ring64 + (size_t)((t - 1) & (RING - 1)) * (B_ * H_ / 4), Bh, acc,
                ib, quad, l15);
      // elemwise + h1 store into ring slot t
      elem_store(acc, bias4, cst, hvv, ring32,
                 (unsigned)(t & (RING - 1)) * (B_ * H_ / 2), k8, rowbase, l15);
      asm volatile("s_waitcnt vmcnt(0)" ::: "memory");
      __hip_atomic_store(sigP, (unsigned)(t + 1), AQ, SC);
    }
    return;
  }

  // ================= L1: two-wave worker pair =================
  const int pair = wv >> 1;
  const int wid = (blockIdx.x - 64) * 2 + pair;
  const int ib = wid >> 5, jn = wid & 31;
  float* const Pb0 = &Pp[pair][0][0];
  float* const Pb1 = &Pp[pair][1][0];
  unsigned* const seq = &seqf[pair];
  const int k8 = jn * 2 + (l15 >> 3);
  const int rowbase = ib * 32 + quad * 4;

  if (!(wv & 1)) {
    // ---- wave0: input GEMM + combine + elemwise + signal ----
    bf16x8 Bx[16][4];
    loadW(Bx, wih1, jn, quad, l15);
    float bias4[4];
#pragma unroll
    for (int g = 0; g < 4; ++g) bias4[g] = b1[g * 512 + jn * 16 + l15];
    float cst[2][4] = {{0.f, 0.f, 0.f, 0.f}, {0.f, 0.f, 0.f, 0.f}};
    float hvv[2][4];
    const unsigned* pollP = IN1 + (unsigned)wid * 64 + lane;
    unsigned* sigP = (lane < 32)
        ? (REC1 + (unsigned)(ib * 32 + lane) * 64 + jn)
        : (REC0 + (unsigned)(ib * 32 + (lane - 32)) * 64 + 32 + jn);
    const u64* ring64 = (const u64*)h1ring;

    for (int t = 0; t < T_; ++t) {
      {
        const unsigned tg = (lane < 32) ? (unsigned)(t + 1) : 0u;
        while (__any(__hip_atomic_load(pollP, AQ, SC) < tg)) {}
      }
      f32x4 acc[2][4];
#pragma unroll
      for (int mt = 0; mt < 2; ++mt)
#pragma unroll
        for (int nt = 0; nt < 4; ++nt) acc[mt][nt] = zf;
      // input GEMM from ring slot t
      gemm512(ring64 + (size_t)(t & (RING - 1)) * (B_ * H_ / 4), Bx, acc, ib, quad, l15);
      // combine wave1's rec partials (LDS handoff, double-buffered)
      if (t) {
        while (__hip_atomic_load(seq, __ATOMIC_ACQUIRE, __HIP_MEMORY_SCOPE_WORKGROUP)
               < (unsigned)(t + 1)) {}
        const float* Pbr = (t & 1) ? Pb1 : Pb0;
#pragma unroll
        for (int mt = 0; mt < 2; ++mt)
#pragma unroll
          for (int nt = 0; nt < 4; ++nt)
#pragma unroll
            for (int rr = 0; rr < 4; ++rr)
              acc[mt][nt][rr] += Pbr[(mt * 16 + quad * 4 + rr) * 68 + nt * 16 + l15];
      }
      // elemwise + h2 store into hx parity buffer
      elem_store(acc, bias4, cst, hvv, hx32,
                 (unsigned)((t + 1) & 1) * (B_ * H_ / 2), k8, rowbase, l15);
      if (t == T_ - 1) {
        float w = Wfc[jn * 16 + l15];
#pragma unroll
        for (int mt = 0; mt < 2; ++mt)
#pragma unroll
          for (int rr = 0; rr < 4; ++rr) {
            float part = hvv[mt][rr] * w;
            part += __shfl_down(part, 8, 16);
            part += __shfl_down(part, 4, 16);
            part += __shfl_down(part, 2, 16);
            part += __shfl_down(part, 1, 16);
            if (l15 == 0) atomicAdd(&out[rowbase + mt * 16 + rr], part);
          }
      }
      asm volatile("s_waitcnt vmcnt(0)" ::: "memory");
      __hip_atomic_store(sigP, (unsigned)(t + 1), AQ, SC);
    }
  } else {
    // ---- wave1: recurrent GEMM producer ----
    bf16x8 Bh[16][4];
    loadW(Bh, whh1, jn, quad, l15);
    const unsigned* pollP = REC1 + (unsigned)wid * 64 + lane;
    const u64* hx64 = (const u64*)hx32;
    for (int t = 1; t < T_; ++t) {
      const unsigned tg = (lane < 32) ? (unsigned)t : 0u;
      while (__any(__hip_atomic_load(pollP, AQ, SC) < tg)) {}
      f32x4 acc[2][4];
#pragma unroll
      for (int mt = 0; mt < 2; ++mt)
#pragma unroll
        for (int nt = 0; nt < 4; ++nt) acc[mt][nt] = zf;
      gemm512(hx64 + (size_t)(t & 1) * (B_ * H_ / 4), Bh, acc, ib, quad, l15);
      float* Pw = (t & 1) ? Pb1 : Pb0;
#pragma unroll
      for (int mt = 0; mt < 2; ++mt)
#pragma unroll
        for (int nt = 0; nt < 4; ++nt)
#pragma unroll
          for (int rr = 0; rr < 4; ++rr)
            Pw[(mt * 16 + quad * 4 + rr) * 68 + nt * 16 + l15] = acc[mt][nt][rr];
      __hip_atomic_store(seq, (unsigned)(t + 1), __ATOMIC_RELEASE,
                         __HIP_MEMORY_SCOPE_WORKGROUP);
    }
  }
}

extern "C" void kernel_launch(void* const* d_in, const int* in_sizes, int n_in,
                              void* d_out, int out_size, void* d_ws, size_t ws_size,
                              hipStream_t stream) {
  if (ws_size < (size_t)WS_NEEDED) return;

  const float* x    = (const float*)d_in[0];
  const float* Wih0 = (const float*)d_in[1];
  const float* Whh0 = (const float*)d_in[2];
  const float* bih0 = (const float*)d_in[3];
  const float* bhh0 = (const float*)d_in[4];
  const float* Wih1 = (const float*)d_in[5];
  const float* Whh1 = (const float*)d_in[6];
  const float* bih1 = (const float*)d_in[7];
  const float* bhh1 = (const float*)d_in[8];
  const float* Wfc  = (const float*)d_in[9];
  const float* bfc  = (const float*)d_in[10];

  char* ws = (char*)d_ws;
  unsigned* rec0 = (unsigned*)(ws + OFF_REC0);
  unsigned* in1  = (unsigned*)(ws + OFF_IN1);
  unsigned* rec1 = (unsigned*)(ws + OFF_REC1);
  float* b0      = (float*)(ws + OFF_B0);
  float* b1      = (float*)(ws + OFF_B1);
  u16* wih0b     = (u16*)(ws + OFF_WIH0);
  u16* whh0b     = (u16*)(ws + OFF_WHH0);
  u16* wih1b     = (u16*)(ws + OFF_WIH1);
  u16* whh1b     = (u16*)(ws + OFF_WHH1);
  unsigned* hx1  = (unsigned*)(ws + OFF_HX1);
  u16* h1ring    = (u16*)(ws + OFF_H1R);
  float* out     = (float*)d_out;

  // prep: 49152 + 256 + 2048*2 + 131072 + 3*1048576 = 3,330,304 elements = 13009 blocks
  prep_kernel<<<13009, 256, 0, stream>>>(Wih0, Whh0, bih0, bhh0, Wih1, Whh1, bih1, bhh1,
                                         bfc, out, ws);

  lstm_fused<<<192, 256, 0, stream>>>(x, wih0b, whh0b, b0, wih1b, whh1b, b1,
                                      hx1, h1ring, Wfc, out, rec0, in1, rec1);
}

// Round 6
// 2496.541 us; speedup vs baseline: 1.8667x; 1.8667x over previous
//
#include <hip/hip_runtime.h>

typedef unsigned short u16;
typedef unsigned long long u64;
typedef short bf16x8 __attribute__((ext_vector_type(8)));
typedef float f32x4 __attribute__((ext_vector_type(4)));

#define B_ 256
#define T_ 512
#define I_ 64
#define H_ 512
#define RING 32

// ---------------- ws layout (bytes) ---------------- (identical to R4)
#define OFF_F0    0u
#define OFF_F1    32768u
#define OFF_F2    65536u
#define OFF_F3    98304u
#define OFF_B0    131072u
#define OFF_B1    139264u
#define OFF_WIH0  147456u
#define OFF_WHH0  409600u
#define OFF_WIH1  2506752u
#define OFF_WHH1  4603904u
#define OFF_HX1   6701056u
#define OFF_H1R   7225344u
#define WS_NEEDED 15613952u

#define AQ __ATOMIC_RELAXED
#define SC __HIP_MEMORY_SCOPE_AGENT

static __device__ __forceinline__ u16 f2b(float f) {
  union { float f; unsigned u; } v; v.f = f;
  unsigned r = (v.u + 0x7FFFu + ((v.u >> 16) & 1u)) >> 16;
  return (u16)r;
}
static __device__ __forceinline__ float sigm(float x) { return 1.f / (1.f + __expf(-x)); }
static __device__ __forceinline__ float tanh_(float x) { return 1.f - 2.f / (__expf(2.f * x) + 1.f); }

// pipelined spin: 2 outstanding flag loads -> sampling period ~RTT/2
static __device__ __forceinline__ void spin2(const unsigned* __restrict__ pa, unsigned tg) {
  unsigned a = __hip_atomic_load(pa, AQ, SC);
  for (;;) {
    unsigned b = __hip_atomic_load(pa, AQ, SC);
    if (!__any(a < tg)) break;
    a = __hip_atomic_load(pa, AQ, SC);
    if (!__any(b < tg)) break;
  }
}

// ---------------- prep: bf16 weights, bias sums, flag zero, out=bfc ----------------
__global__ void prep_kernel(const float* __restrict__ Wih0, const float* __restrict__ Whh0,
                            const float* __restrict__ bih0, const float* __restrict__ bhh0,
                            const float* __restrict__ Wih1, const float* __restrict__ Whh1,
                            const float* __restrict__ bih1, const float* __restrict__ bhh1,
                            const float* __restrict__ bfc, float* __restrict__ out,
                            char* __restrict__ ws) {
  unsigned* flags = (unsigned*)(ws + OFF_F0);
  float* b0 = (float*)(ws + OFF_B0);
  float* b1 = (float*)(ws + OFF_B1);
  u16* wih0b = (u16*)(ws + OFF_WIH0);
  u16* whh0b = (u16*)(ws + OFF_WHH0);
  u16* wih1b = (u16*)(ws + OFF_WIH1);
  u16* whh1b = (u16*)(ws + OFF_WHH1);

  long long i = (long long)blockIdx.x * 256 + threadIdx.x;
  if (i < 32768) { __hip_atomic_store(&flags[i], 0u, AQ, SC); return; }
  i -= 32768;
  if (i < 256) { out[i] = bfc[0]; return; }
  i -= 256;
  if (i < 2048) { b0[i] = bih0[i] + bhh0[i]; return; }
  i -= 2048;
  if (i < 2048) { b1[i] = bih1[i] + bhh1[i]; return; }
  i -= 2048;
  if (i < 131072) { wih0b[i] = f2b(Wih0[i]); return; }
  i -= 131072;
  if (i < 1048576) { whh0b[i] = f2b(Whh0[i]); return; }
  i -= 1048576;
  if (i < 1048576) { wih1b[i] = f2b(Wih1[i]); return; }
  i -= 1048576;
  if (i < 1048576) { whh1b[i] = f2b(Whh1[i]); return; }
}

// ---------------- fused 2-layer pipelined LSTM (R4 skeleton) ----------------
// Per step: [input GEMM] -> wave0 dual-spin -> barA -> setprio1 -> rec GEMM ->
// vec dump (col-major Gp) -> barB -> elemwise + h store -> setprio0 -> barC (drain)
// -> wave0 block-granular signal. L1 prefetches fP>=t+2 so input GEMM needs no check.
template <bool IS_L0>
__device__ __forceinline__ void lstm_body(
    int bx,
    const float* __restrict__ x,
    const u16* __restrict__ Wib,
    const u16* __restrict__ Whb,
    const float* __restrict__ bias,
    unsigned* __restrict__ hx32,
    u16* __restrict__ h1ring,
    const float* __restrict__ Wfc, float* __restrict__ out,
    unsigned* __restrict__ fR,
    unsigned* __restrict__ fP,
    unsigned* __restrict__ fC,
    float* __restrict__ Gp_s)         // [64 cols][132 rows] f32 (col-major, padded)
{
  const int tid = threadIdx.x;
  const int wv = tid >> 6;
  const int lane = tid & 63;
  const int quad = lane >> 4;
  const int l15 = lane & 15;
  const int jn = bx & 31;
  const int ib = bx >> 5;

  bf16x8 Bh[4][4];
#pragma unroll
  for (int r = 0; r < 4; ++r)
#pragma unroll
    for (int nt = 0; nt < 4; ++nt)
      Bh[r][nt] = *(const bf16x8*)&Whb[(size_t)(nt * 512 + jn * 16 + l15) * 512 +
                                       (wv * 4 + r) * 32 + quad * 8];
  bf16x8 Bx[4][4];
  bf16x8 Bx0[4];
  if constexpr (IS_L0) {
    if (wv < 2) {
#pragma unroll
      for (int nt = 0; nt < 4; ++nt)
        Bx0[nt] = *(const bf16x8*)&Wib[(size_t)(nt * 512 + jn * 16 + l15) * 64 +
                                       wv * 32 + quad * 8];
    }
  } else {
#pragma unroll
    for (int r = 0; r < 4; ++r)
#pragma unroll
      for (int nt = 0; nt < 4; ++nt)
        Bx[r][nt] = *(const bf16x8*)&Wib[(size_t)(nt * 512 + jn * 16 + l15) * 512 +
                                         (wv * 4 + r) * 32 + quad * 8];
  }

  const int erow = tid >> 3;
  const int ecp = tid & 7;
  float bias2[4][2];
#pragma unroll
  for (int g = 0; g < 4; ++g) {
    bias2[g][0] = bias[g * 512 + jn * 16 + 2 * ecp];
    bias2[g][1] = bias[g * 512 + jn * 16 + 2 * ecp + 1];
  }
  float cst2[2] = {0.f, 0.f};
  const f32x4 zf = {0.f, 0.f, 0.f, 0.f};
  const unsigned lineoff = ((unsigned)ib * 32 + jn) * 32;

  const int bg = ib * 32 + erow;
  const int hg = jn * 16 + 2 * ecp;
  const unsigned stoff = (unsigned)(((hg >> 3) * 256 + bg) * 4 + (ecp & 3));

  // per-lane dual-spin pointers (wave0): lanes<32 = fR; lanes>=32 = fC (L0) / fP (L1)
  const unsigned* pollP;
  if constexpr (IS_L0)
    pollP = (lane < 32) ? &fR[lineoff + lane] : &fC[lineoff + (lane - 32)];
  else
    pollP = (lane < 32) ? &fR[lineoff + lane] : &fP[lineoff + (lane - 32)];

  if constexpr (!IS_L0) {
    // pre-loop: confirm fP >= 1 so iteration 0's input GEMM may read ring slot 0
    if (wv == 0) spin2(&fP[lineoff + (lane & 31)], 1u);
    __syncthreads();
  }

  for (int t = 0; t < T_; ++t) {
    f32x4 acc[2][4];
#pragma unroll
    for (int mt = 0; mt < 2; ++mt)
#pragma unroll
      for (int nt = 0; nt < 4; ++nt) acc[mt][nt] = zf;

    if constexpr (IS_L0) {
      // x(t) -> regs; input GEMM before the poll (h-independent)
      if (wv < 2) {
        const float* xp = x + ((size_t)(ib * 32 + l15) * T_ + t) * 64 + wv * 32 + quad * 8;
        const float* xq = xp + (size_t)16 * T_ * 64;
        float4 xa = *(const float4*)xp;
        float4 xb = *(const float4*)(xp + 4);
        float4 xc = *(const float4*)xq;
        float4 xd = *(const float4*)(xq + 4);
        union { unsigned u[4]; bf16x8 v; } P0, P1;
        P0.u[0] = (unsigned)f2b(xa.x) | ((unsigned)f2b(xa.y) << 16);
        P0.u[1] = (unsigned)f2b(xa.z) | ((unsigned)f2b(xa.w) << 16);
        P0.u[2] = (unsigned)f2b(xb.x) | ((unsigned)f2b(xb.y) << 16);
        P0.u[3] = (unsigned)f2b(xb.z) | ((unsigned)f2b(xb.w) << 16);
        P1.u[0] = (unsigned)f2b(xc.x) | ((unsigned)f2b(xc.y) << 16);
        P1.u[1] = (unsigned)f2b(xc.z) | ((unsigned)f2b(xc.w) << 16);
        P1.u[2] = (unsigned)f2b(xd.x) | ((unsigned)f2b(xd.y) << 16);
        P1.u[3] = (unsigned)f2b(xd.z) | ((unsigned)f2b(xd.w) << 16);
#pragma unroll
        for (int nt = 0; nt < 4; ++nt) {
          acc[0][nt] = __builtin_amdgcn_mfma_f32_16x16x32_bf16(P0.v, Bx0[nt], acc[0][nt], 0, 0, 0);
          acc[1][nt] = __builtin_amdgcn_mfma_f32_16x16x32_bf16(P1.v, Bx0[nt], acc[1][nt], 0, 0, 0);
        }
      }
      // wave0 dual-spin: fR >= t ; fC >= t-RING+1
      if (t && wv == 0) {
        const unsigned tg = (lane < 32) ? (unsigned)t
                            : ((t >= RING) ? (unsigned)(t - RING + 1) : 0u);
        spin2(pollP, tg);
      }
      __syncthreads();   // barA
    } else {
      // input GEMM from ring slot t (validity: fP>=t+1 confirmed by prev iter's spin)
      const u64* hq1 = (const u64*)h1ring + (size_t)(t & (RING - 1)) * (B_ * H_ / 4);
#pragma unroll
      for (int r = 0; r < 4; ++r) {
        int ks = wv * 4 + r;
        bf16x8 af[2];
#pragma unroll
        for (int mt = 0; mt < 2; ++mt) {
          const u64* p = hq1 + (size_t)((ks * 4 + quad) * 256 + ib * 32 + mt * 16 + l15) * 2;
          union { u64 q[2]; bf16x8 v; } u;
          u.q[0] = __hip_atomic_load(p, AQ, SC);
          u.q[1] = __hip_atomic_load(p + 1, AQ, SC);
          af[mt] = u.v;
        }
#pragma unroll
        for (int nt = 0; nt < 4; ++nt) {
          acc[0][nt] = __builtin_amdgcn_mfma_f32_16x16x32_bf16(af[0], Bx[r][nt], acc[0][nt], 0, 0, 0);
          acc[1][nt] = __builtin_amdgcn_mfma_f32_16x16x32_bf16(af[1], Bx[r][nt], acc[1][nt], 0, 0, 0);
        }
      }
      // wave0 dual-spin: fR >= t ; fP >= min(t+2, T) (prefetch next step's input validity)
      if (wv == 0) {
        unsigned tP = (unsigned)(t + 2); if (tP > (unsigned)T_) tP = (unsigned)T_;
        const unsigned tg = (lane < 32) ? (unsigned)t : tP;
        spin2(pollP, tg);
      }
      __syncthreads();   // barA
    }

    __builtin_amdgcn_s_setprio(1);

    // ---- recurrent GEMM: L0 reads ring slot (t-1)&31, L1 its parity buffer
    if (t) {
      const u64* hq;
      if constexpr (IS_L0)
        hq = (const u64*)h1ring + (size_t)((t - 1) & (RING - 1)) * (B_ * H_ / 4);
      else
        hq = (const u64*)hx32 + (size_t)(t & 1) * (B_ * H_ / 4);
      bf16x8 af[4][2];
#pragma unroll
      for (int r = 0; r < 4; ++r) {
        int ks = wv * 4 + r;
#pragma unroll
        for (int mt = 0; mt < 2; ++mt) {
          const u64* p = hq + (size_t)((ks * 4 + quad) * 256 + ib * 32 + mt * 16 + l15) * 2;
          union { u64 q[2]; bf16x8 v; } u;
          u.q[0] = __hip_atomic_load(p, AQ, SC);
          u.q[1] = __hip_atomic_load(p + 1, AQ, SC);
          af[r][mt] = u.v;
        }
      }
#pragma unroll
      for (int r = 0; r < 4; ++r)
#pragma unroll
        for (int mt = 0; mt < 2; ++mt)
#pragma unroll
          for (int nt = 0; nt < 4; ++nt)
            acc[mt][nt] = __builtin_amdgcn_mfma_f32_16x16x32_bf16(af[r][mt], Bh[r][nt],
                                                                  acc[mt][nt], 0, 0, 0);
    }

    // ---- vectorized dump, col-major Gp[64 cols][132 rows]: ds_write_b128, 2-way free
#pragma unroll
    for (int mt = 0; mt < 2; ++mt)
#pragma unroll
      for (int nt = 0; nt < 4; ++nt)
        *(f32x4*)&Gp_s[(nt * 16 + l15) * 132 + wv * 32 + mt * 16 + quad * 4] = acc[mt][nt];
    __syncthreads();   // barB

    // ---- elemwise: reduce partials (col-major reads, 2-way free), gates, c/h, store h
    {
      float pre[4][2];
#pragma unroll
      for (int g = 0; g < 4; ++g) {
#pragma unroll
        for (int j = 0; j < 2; ++j) {
          const int c = g * 16 + 2 * ecp + j;
          float s = bias2[g][j];
#pragma unroll
          for (int w = 0; w < 4; ++w) s += Gp_s[c * 132 + w * 32 + erow];
          pre[g][j] = s;
        }
      }
      float hv[2];
#pragma unroll
      for (int j = 0; j < 2; ++j) {
        float iv = sigm(pre[0][j]);
        float fv = sigm(pre[1][j]);
        float gv = tanh_(pre[2][j]);
        float ov = sigm(pre[3][j]);
        float cn = fv * cst2[j] + iv * gv;
        cst2[j] = cn;
        hv[j] = ov * tanh_(cn);
      }
      unsigned pack = (unsigned)f2b(hv[0]) | ((unsigned)f2b(hv[1]) << 16);
      if constexpr (IS_L0) {
        unsigned* ring32 = (unsigned*)h1ring;
        __hip_atomic_store(&ring32[(size_t)(t & (RING - 1)) * (B_ * H_ / 2) + stoff],
                           pack, AQ, SC);
      } else {
        __hip_atomic_store(&hx32[(size_t)((t + 1) & 1) * (B_ * H_ / 2) + stoff], pack, AQ, SC);
        if (t == T_ - 1) {
          float part = hv[0] * Wfc[hg] + hv[1] * Wfc[hg + 1];
          part += __shfl_down(part, 4, 8);
          part += __shfl_down(part, 2, 8);
          part += __shfl_down(part, 1, 8);
          if (ecp == 0) atomicAdd(&out[bg], part);
        }
      }
    }
    __builtin_amdgcn_s_setprio(0);

    // ---- barC drains all waves' h stores (syncthreads implies vmcnt(0)), then signal
    __syncthreads();
    if (wv == 0) {
      unsigned val = (unsigned)(t + 1);
      if constexpr (IS_L0) {
        if (lane < 32)
          __hip_atomic_store(&fR[((unsigned)ib * 32 + lane) * 32 + jn], val, AQ, SC);
        else
          __hip_atomic_store(&fP[((unsigned)ib * 32 + (lane - 32)) * 32 + jn], val, AQ, SC);
      } else {
        if (lane < 32)
          __hip_atomic_store(&fR[((unsigned)ib * 32 + lane) * 32 + jn], val, AQ, SC);
        else
          __hip_atomic_store(&fC[((unsigned)ib * 32 + (lane - 32)) * 32 + jn], val, AQ, SC);
      }
    }
  }
}

__global__ __launch_bounds__(256, 2) void lstm_fused(
    const float* __restrict__ x,
    const u16* __restrict__ wih0, const u16* __restrict__ whh0, const float* __restrict__ b0,
    const u16* __restrict__ wih1, const u16* __restrict__ whh1, const float* __restrict__ b1,
    unsigned* __restrict__ hx1, u16* __restrict__ h1ring,
    const float* __restrict__ Wfc, float* __restrict__ out,
    unsigned* __restrict__ f0, unsigned* __restrict__ f1, unsigned* __restrict__ f2,
    unsigned* __restrict__ f3)
{
  __shared__ __align__(16) float Gp_s[64 * 132];
  if (blockIdx.x < 256)
    lstm_body<true>(blockIdx.x, x, wih0, whh0, b0, (unsigned*)nullptr, h1ring,
                    (const float*)nullptr, (float*)nullptr, f0, f1, f3, Gp_s);
  else
    lstm_body<false>(blockIdx.x - 256, (const float*)nullptr, wih1, whh1, b1, hx1, h1ring,
                     Wfc, out, f2, f1, f3, Gp_s);
}

extern "C" void kernel_launch(void* const* d_in, const int* in_sizes, int n_in,
                              void* d_out, int out_size, void* d_ws, size_t ws_size,
                              hipStream_t stream) {
  if (ws_size < (size_t)WS_NEEDED) return;

  const float* x    = (const float*)d_in[0];
  const float* Wih0 = (const float*)d_in[1];
  const float* Whh0 = (const float*)d_in[2];
  const float* bih0 = (const float*)d_in[3];
  const float* bhh0 = (const float*)d_in[4];
  const float* Wih1 = (const float*)d_in[5];
  const float* Whh1 = (const float*)d_in[6];
  const float* bih1 = (const float*)d_in[7];
  const float* bhh1 = (const float*)d_in[8];
  const float* Wfc  = (const float*)d_in[9];
  const float* bfc  = (const float*)d_in[10];

  char* ws = (char*)d_ws;
  unsigned* f0   = (unsigned*)(ws + OFF_F0);
  unsigned* f1   = (unsigned*)(ws + OFF_F1);
  unsigned* f2   = (unsigned*)(ws + OFF_F2);
  unsigned* f3   = (unsigned*)(ws + OFF_F3);
  float* b0      = (float*)(ws + OFF_B0);
  float* b1      = (float*)(ws + OFF_B1);
  u16* wih0b     = (u16*)(ws + OFF_WIH0);
  u16* whh0b     = (u16*)(ws + OFF_WHH0);
  u16* wih1b     = (u16*)(ws + OFF_WIH1);
  u16* whh1b     = (u16*)(ws + OFF_WHH1);
  unsigned* hx1  = (unsigned*)(ws + OFF_HX1);
  u16* h1ring    = (u16*)(ws + OFF_H1R);
  float* out     = (float*)d_out;

  prep_kernel<<<12948, 256, 0, stream>>>(Wih0, Whh0, bih0, bhh0, Wih1, Whh1, bih1, bhh1,
                                         bfc, out, ws);

  lstm_fused<<<512, 256, 0, stream>>>(x, wih0b, whh0b, b0, wih1b, whh1b, b1,
                                      hx1, h1ring, Wfc, out, f0, f1, f2, f3);
}